// Round 8
// baseline (176.622 us; speedup 1.0000x reference)
//
#include <hip/hip_runtime.h>
#include <hip/hip_bf16.h>
#include <hip/hip_fp16.h>
#include <type_traits>

// f32 in / f32 out. Round-11: OCCUPANCY RESTRUCTURE. r10 lesson: h2 "packed"
// epilogue scalarizes (VALU busy time rose) -> revert to f32 mish (r7 form).
// Real limiter: 64 VGPR + 16 AGPR ~ 80 unified regs -> 65-128 bucket -> only
// 4 waves/SIMD, VALUBusy stuck at 56% with 43% idle issue slots. Fix by
// design, not force: 1024-thread blocks, 16 waves, each wave owns 16 hidden
// cols -> bfrag 16, acc 8 AGPR, b1/w2 4 -> natural ~55-60 regs <= 64 ->
// __launch_bounds__(1024,8) gives 8 waves/SIMD legally (r1 spilled because
// natural was ~80+16; here the margin is positive). GRID=512 = 2 blocks/CU =
// 32 waves/CU. Same work/byte counts; gather is 8 B/thread (32 thr/row).
// Keeps: swapped MFMA (r7), fp16 z pre-pass, pre-barrier prefetch (r10),
// double-buffered LDS, ONE barrier per tile, M_TILE=32.

#define N_NODES 100000
#define N_EDGES 500000
#define D_IN    128
#define D_HID   256
#define M_TILE  32
#define NTILES  (N_EDGES / M_TILE)   // 15625 exactly, no partial tile
#define LDS_STRIDE 136               // 128 + 8 elements pad (2B elements)
#define GRID    512                  // 2 blocks/CU resident
#define NWAVES  16

typedef _Float16 half8  __attribute__((ext_vector_type(8)));
typedef _Float16 half4  __attribute__((ext_vector_type(4)));
typedef __bf16   bf16x8 __attribute__((ext_vector_type(8)));
typedef float    f32x4  __attribute__((ext_vector_type(4)));
typedef float    f32x2  __attribute__((ext_vector_type(2)));

union F4H { float4 v; f32x2 h[2]; };

__device__ __forceinline__ unsigned int pkbf(f32x2 q) {
    union { __hip_bfloat162 b; unsigned int u; } c;
    c.b = __float22bfloat162_rn(make_float2(q.x, q.y));   // RNE packed cvt
    return c.u;
}

// mish(x) = x * N/(N+2), N = E*(E+2), E = e^x — float2-vectorized (r7 form)
__device__ __forceinline__ f32x2 mish2(f32x2 x) {
    f32x2 xc = {fminf(x.x, 20.0f), fminf(x.y, 20.0f)};
    f32x2 E  = {__expf(xc.x), __expf(xc.y)};
    f32x2 num = E * (E + 2.0f);
    f32x2 den = num + 2.0f;
    f32x2 r  = {__builtin_amdgcn_rcpf(den.x), __builtin_amdgcn_rcpf(den.y)};
    return x * num * r;
}

// ---- pre-pass: z f32 -> fp16 (RNE), fully coalesced, BW-bound ----
__global__ __launch_bounds__(256)
void zcvt_kernel(const float* __restrict__ z, _Float16* __restrict__ zh) {
    const size_t i = (size_t)blockIdx.x * 256 + threadIdx.x;   // chunk id
    const float4 f0 = *reinterpret_cast<const float4*>(z + i * 8);
    const float4 f1 = *reinterpret_cast<const float4*>(z + i * 8 + 4);
    union { half8 h; uint4 u; } o;
    o.h[0] = (_Float16)f0.x; o.h[1] = (_Float16)f0.y;
    o.h[2] = (_Float16)f0.z; o.h[3] = (_Float16)f0.w;
    o.h[4] = (_Float16)f1.x; o.h[5] = (_Float16)f1.y;
    o.h[6] = (_Float16)f1.z; o.h[7] = (_Float16)f1.w;
    *reinterpret_cast<uint4*>(zh + i * 8) = o.u;
}

template <bool USE_H>
__global__ __launch_bounds__(1024, 8)
void edge_decoder_kernel(const float*    __restrict__ z,
                         const _Float16* __restrict__ zh,
                         const int*      __restrict__ edge,
                         const float*    __restrict__ W1,
                         const float*    __restrict__ b1,
                         const float*    __restrict__ W2,
                         const float*    __restrict__ b2,
                         float*          __restrict__ out) {
    using frag_t = std::conditional_t<USE_H, half8, bf16x8>;

    __shared__ ushort xbuf[2][M_TILE * LDS_STRIDE];   // 2 x 8.7 KB
    __shared__ float  lpart[2][NWAVES][M_TILE];       // 4 KB

    const int t    = threadIdx.x;
    const int wave = t >> 6;          // 0..15
    const int lane = t & 63;
    const int quad = lane >> 4;
    const int nlo  = lane & 15;

    // ---- W1 -> fragment (wave owns hidden cols [16w, 16w+16)) ----
    // A-operand of the swapped mfma: lane l&15 = W1 row (hidden).
    frag_t bfrag[4];                  // [ks] = 16 VGPRs
    {
        const int n = wave * 16 + nlo;
        const float* wrow = W1 + n * D_IN;
        #pragma unroll
        for (int ks = 0; ks < 4; ++ks) {
            float4 w0 = *reinterpret_cast<const float4*>(wrow + ks * 32 + quad * 8);
            float4 w1 = *reinterpret_cast<const float4*>(wrow + ks * 32 + quad * 8 + 4);
            float wa[8] = {w0.x, w0.y, w0.z, w0.w, w1.x, w1.y, w1.z, w1.w};
            if constexpr (USE_H) {
                half8 hv;
                #pragma unroll
                for (int j = 0; j < 8; ++j) hv[j] = (_Float16)wa[j];
                bfrag[ks] = hv;
            } else {
                bf16x8 bv;
                #pragma unroll
                for (int j = 0; j < 8; ++j) bv[j] = (__bf16)wa[j];
                bfrag[ks] = bv;
            }
        }
    }
    // Swapped-D layout: lane holds hidden rows {quad*4 + r} of its wave's 16.
    f32x2 b1p[2], w2p[2];
    {
        const int nb = wave * 16 + quad * 4;
        b1p[0] = (f32x2){b1[nb],     b1[nb + 1]};
        b1p[1] = (f32x2){b1[nb + 2], b1[nb + 3]};
        w2p[0] = (f32x2){W2[nb],     W2[nb + 1]};
        w2p[1] = (f32x2){W2[nb + 2], W2[nb + 3]};
    }
    const float b2f = b2[0];

    // ---- gather assignment: 32 threads per edge row, 4 halves each ----
    const int s_slot = t >> 5;        // 0..31 edge slot in tile
    const int cch    = t & 31;        // 0..31 4-elem chunk

    // ---- pipeline prologue ----
    int tile = blockIdx.x;
    float4 a0, c0;                    // f32 path gather regs (16B = 4 floats)
    half4  ha, hc;                    // fp16 path gather regs (8B)
    {
        const int e = tile * M_TILE + s_slot;
        const int u = edge[e], v = edge[N_EDGES + e];
        if constexpr (USE_H) {
            ha = *reinterpret_cast<const half4*>(zh + (size_t)u * D_IN + cch * 4);
            hc = *reinterpret_cast<const half4*>(zh + (size_t)v * D_IN + cch * 4);
        } else {
            a0 = *reinterpret_cast<const float4*>(z + (size_t)u * D_IN + cch * 4);
            c0 = *reinterpret_cast<const float4*>(z + (size_t)v * D_IN + cch * 4);
        }
    }
    // next tile's gather addresses: USE_H stores precomputed BYTE offsets.
    int u_n, v_n;
    {
        const int t1 = min(tile + GRID, NTILES - 1);
        const int e1 = t1 * M_TILE + s_slot;
        if constexpr (USE_H) {
            u_n = edge[e1] * 256 + cch * 8;
            v_n = edge[N_EDGES + e1] * 256 + cch * 8;
        } else {
            u_n = edge[e1]; v_n = edge[N_EDGES + e1];
        }
    }

    int  p = 0;
    bool have_prev = false;
    int  prev_base = 0;

    for (; tile < NTILES; tile += GRID) {
        // ---- A: current tile's gathered pair-product -> xbuf[p] ----
        if constexpr (USE_H) {
            union { half4 h; uint2 u; } pr;
            pr.h = ha * hc;                       // 2x v_pk_mul_f16
            *reinterpret_cast<uint2*>(&xbuf[p][s_slot * LDS_STRIDE + cch * 4]) = pr.u;
        } else {
            F4H A0{a0}, C0{c0};
            unsigned int r0 = pkbf(A0.h[0] * C0.h[0]);
            unsigned int r1 = pkbf(A0.h[1] * C0.h[1]);
            *reinterpret_cast<uint2*>(&xbuf[p][s_slot * LDS_STRIDE + cch * 4]) =
                make_uint2(r0, r1);
        }

        // ---- C (pre-barrier): issue next tile's z loads + edge idx t+2 ----
        if constexpr (USE_H) {
            ha = *reinterpret_cast<const half4*>(
                     reinterpret_cast<const char*>(zh) + u_n);
            hc = *reinterpret_cast<const half4*>(
                     reinterpret_cast<const char*>(zh) + v_n);
        } else {
            a0 = *reinterpret_cast<const float4*>(z + (size_t)u_n * D_IN + cch * 4);
            c0 = *reinterpret_cast<const float4*>(z + (size_t)v_n * D_IN + cch * 4);
        }
        {
            const int t2 = min(tile + 2 * GRID, NTILES - 1);
            const int e2 = t2 * M_TILE + s_slot;
            if constexpr (USE_H) {
                u_n = edge[e2] * 256 + cch * 8;
                v_n = edge[N_EDGES + e2] * 256 + cch * 8;
            } else {
                u_n = edge[e2]; v_n = edge[N_EDGES + e2];
            }
        }

        // ---- B: the single barrier ----
        __syncthreads();

        // ---- E: combine + store PREVIOUS tile (lpart[p^1] sealed by barrier) ----
        if (have_prev) {
            if (t < M_TILE) {
                const int pp = p ^ 1;
                float logit = b2f;
                #pragma unroll
                for (int w = 0; w < NWAVES; ++w) logit += lpart[pp][w][t];
                out[prev_base + t] = __builtin_amdgcn_rcpf(1.0f + __expf(-logit));
            }
        }

        // ---- D: swapped MFMA + f32 epilogue -> lpart[p] ----
        f32x4 acc[2];   // [mt]; D row = hidden (quad*4+r), col = edge (nlo)
        acc[0] = (f32x4){0.f, 0.f, 0.f, 0.f};
        acc[1] = (f32x4){0.f, 0.f, 0.f, 0.f};

        #pragma unroll
        for (int ks = 0; ks < 4; ++ks) {
            frag_t af[2];   // x-fragment: lane l&15 = edge row mt*16+nlo
            #pragma unroll
            for (int mt = 0; mt < 2; ++mt)
                af[mt] = *reinterpret_cast<const frag_t*>(
                    &xbuf[p][(mt * 16 + nlo) * LDS_STRIDE + ks * 32 + quad * 8]);
            #pragma unroll
            for (int mt = 0; mt < 2; ++mt) {
                if constexpr (USE_H)
                    acc[mt] = __builtin_amdgcn_mfma_f32_16x16x32_f16(
                        bfrag[ks], af[mt], acc[mt], 0, 0, 0);
                else
                    acc[mt] = __builtin_amdgcn_mfma_f32_16x16x32_bf16(
                        bfrag[ks], af[mt], acc[mt], 0, 0, 0);
            }
        }

        // Epilogue: lane-local mish + fc2 dot over this lane's 4 hidden rows,
        // then 2-step cross-quad reduce (xor16, xor32). Edge = mt*16 + nlo.
        #pragma unroll
        for (int mt = 0; mt < 2; ++mt) {
            f32x2 h0 = (f32x2){acc[mt][0], acc[mt][1]} + b1p[0];
            f32x2 h1 = (f32x2){acc[mt][2], acc[mt][3]} + b1p[1];
            f32x2 m0 = mish2(h0);
            f32x2 m1 = mish2(h1);
            f32x2 dot = m0 * w2p[0] + m1 * w2p[1];
            float s = dot.x + dot.y;
            s += __shfl_xor(s, 16);
            s += __shfl_xor(s, 32);
            if (quad == 0) lpart[p][wave][mt * 16 + nlo] = s;
        }

        have_prev = true;
        prev_base = tile * M_TILE;
        p ^= 1;
    }

    // ---- drain: last tile's logits ----
    __syncthreads();
    if (have_prev && t < M_TILE) {
        const int pp = p ^ 1;
        float logit = b2f;
        #pragma unroll
        for (int w = 0; w < NWAVES; ++w) logit += lpart[pp][w][t];
        out[prev_base + t] = __builtin_amdgcn_rcpf(1.0f + __expf(-logit));
    }
}

extern "C" void kernel_launch(void* const* d_in, const int* in_sizes, int n_in,
                              void* d_out, int out_size, void* d_ws, size_t ws_size,
                              hipStream_t stream) {
    const float* z    = (const float*)d_in[0];
    const int*   edge = (const int*)d_in[1];
    const float* W1   = (const float*)d_in[2];
    const float* b1   = (const float*)d_in[3];
    const float* W2   = (const float*)d_in[4];
    const float* b2   = (const float*)d_in[5];
    float* out = (float*)d_out;

    const size_t zh_bytes = (size_t)N_NODES * D_IN * sizeof(_Float16);  // 25.6 MB
    if (d_ws != nullptr && ws_size >= zh_bytes) {
        _Float16* zh = (_Float16*)d_ws;
        zcvt_kernel<<<dim3(N_NODES * D_IN / 8 / 256), dim3(256), 0, stream>>>(z, zh);
        edge_decoder_kernel<true><<<dim3(GRID), dim3(1024), 0, stream>>>(
            z, zh, edge, W1, b1, W2, b2, out);
    } else {
        edge_decoder_kernel<false><<<dim3(GRID), dim3(1024), 0, stream>>>(
            z, nullptr, edge, W1, b1, W2, b2, out);
    }
}